// Round 1
// baseline (1681.854 us; speedup 1.0000x reference)
//
#include <hip/hip_runtime.h>
#include <math.h>

// Problem constants
#define Bp 32
#define Vp 48
#define Ip 24
#define Hp 768
#define EPS 1e-5f

#define EFFECTS_SIZE (Bp*Ip*Vp*Hp)   // 28,311,552
#define GRAPH_SIZE   (Bp*Vp*Vp)      // 73,728
#define ENC_SIZE     (Bp*Vp*Hp)      // 1,179,648
#define HA_SIZE      (Bp*Ip*Hp)      // 589,824

__device__ __forceinline__ float wave_sum(float v) {
#pragma unroll
    for (int m = 1; m < 64; m <<= 1) v += __shfl_xor(v, m, 64);
    return v;
}

// ---------------------------------------------------------------------------
// Kernel A: enc = relu(LN(variables @ W_enc + b_enc) * g_enc + be_enc)
// 4 rows per block, 256 threads; cols k = tid, tid+256, tid+512
// ---------------------------------------------------------------------------
__global__ __launch_bounds__(256) void enc_kernel(
    const float* __restrict__ Ain, const float* __restrict__ W,
    const float* __restrict__ bias, const float* __restrict__ g,
    const float* __restrict__ be, float* __restrict__ out)
{
    __shared__ float As[4][Hp];
    __shared__ float reds[4][4], redq[4][4];

    const int tid = threadIdx.x;
    const int row0 = blockIdx.x * 4;
    const float* Ab = Ain + (size_t)row0 * Hp;
    float* Asf = &As[0][0];
#pragma unroll
    for (int idx = tid; idx < 4 * Hp; idx += 256) Asf[idx] = Ab[idx];
    __syncthreads();

    float acc[4][3] = {};
    for (int h = 0; h < Hp; h += 2) {
        float2 a[4];
#pragma unroll
        for (int r = 0; r < 4; ++r) a[r] = *reinterpret_cast<const float2*>(&As[r][h]);
#pragma unroll
        for (int u = 0; u < 2; ++u) {
            const float* wrow = W + (size_t)(h + u) * Hp;
            float w0 = wrow[tid], w1 = wrow[tid + 256], w2 = wrow[tid + 512];
#pragma unroll
            for (int r = 0; r < 4; ++r) {
                float av = u ? a[r].y : a[r].x;
                acc[r][0] = fmaf(av, w0, acc[r][0]);
                acc[r][1] = fmaf(av, w1, acc[r][1]);
                acc[r][2] = fmaf(av, w2, acc[r][2]);
            }
        }
    }

    const float bb0 = bias[tid], bb1 = bias[tid + 256], bb2 = bias[tid + 512];
    float pre[4][3];
#pragma unroll
    for (int r = 0; r < 4; ++r) {
        pre[r][0] = acc[r][0] + bb0;
        pre[r][1] = acc[r][1] + bb1;
        pre[r][2] = acc[r][2] + bb2;
    }
    float s[4], q[4];
#pragma unroll
    for (int r = 0; r < 4; ++r) {
        s[r] = pre[r][0] + pre[r][1] + pre[r][2];
        q[r] = pre[r][0]*pre[r][0] + pre[r][1]*pre[r][1] + pre[r][2]*pre[r][2];
    }
#pragma unroll
    for (int m = 1; m < 64; m <<= 1) {
#pragma unroll
        for (int r = 0; r < 4; ++r) {
            s[r] += __shfl_xor(s[r], m, 64);
            q[r] += __shfl_xor(q[r], m, 64);
        }
    }
    const int wave = tid >> 6, lane = tid & 63;
    if (lane == 0) {
#pragma unroll
        for (int r = 0; r < 4; ++r) { reds[wave][r] = s[r]; redq[wave][r] = q[r]; }
    }
    __syncthreads();

    const float g0 = g[tid], g1 = g[tid + 256], g2 = g[tid + 512];
    const float e0 = be[tid], e1 = be[tid + 256], e2 = be[tid + 512];
#pragma unroll
    for (int r = 0; r < 4; ++r) {
        float S = reds[0][r] + reds[1][r] + reds[2][r] + reds[3][r];
        float Q = redq[0][r] + redq[1][r] + redq[2][r] + redq[3][r];
        float mu = S * (1.0f / Hp);
        float var = Q * (1.0f / Hp) - mu * mu;
        float rs = rsqrtf(var + EPS);
        float* orow = out + (size_t)(row0 + r) * Hp;
        orow[tid]       = fmaxf((pre[r][0] - mu) * rs * g0 + e0, 0.0f);
        orow[tid + 256] = fmaxf((pre[r][1] - mu) * rs * g1 + e1, 0.0f);
        orow[tid + 512] = fmaxf((pre[r][2] - mu) * rs * g2 + e2, 0.0f);
    }
}

// ---------------------------------------------------------------------------
// Kernel B: out = A @ W (+ bias), 4 rows/block
// ---------------------------------------------------------------------------
__global__ __launch_bounds__(256) void gemm4_kernel(
    const float* __restrict__ Ain, const float* __restrict__ W,
    const float* __restrict__ bias, float* __restrict__ out)
{
    __shared__ float As[4][Hp];
    const int tid = threadIdx.x;
    const int row0 = blockIdx.x * 4;
    const float* Ab = Ain + (size_t)row0 * Hp;
    float* Asf = &As[0][0];
#pragma unroll
    for (int idx = tid; idx < 4 * Hp; idx += 256) Asf[idx] = Ab[idx];
    __syncthreads();

    float acc[4][3] = {};
    for (int h = 0; h < Hp; h += 2) {
        float2 a[4];
#pragma unroll
        for (int r = 0; r < 4; ++r) a[r] = *reinterpret_cast<const float2*>(&As[r][h]);
#pragma unroll
        for (int u = 0; u < 2; ++u) {
            const float* wrow = W + (size_t)(h + u) * Hp;
            float w0 = wrow[tid], w1 = wrow[tid + 256], w2 = wrow[tid + 512];
#pragma unroll
            for (int r = 0; r < 4; ++r) {
                float av = u ? a[r].y : a[r].x;
                acc[r][0] = fmaf(av, w0, acc[r][0]);
                acc[r][1] = fmaf(av, w1, acc[r][1]);
                acc[r][2] = fmaf(av, w2, acc[r][2]);
            }
        }
    }

    float b0 = 0.f, b1 = 0.f, b2 = 0.f;
    if (bias) { b0 = bias[tid]; b1 = bias[tid + 256]; b2 = bias[tid + 512]; }
#pragma unroll
    for (int r = 0; r < 4; ++r) {
        float* orow = out + (size_t)(row0 + r) * Hp;
        orow[tid]       = acc[r][0] + b0;
        orow[tid + 256] = acc[r][1] + b1;
        orow[tid + 512] = acc[r][2] + b2;
    }
}

// ---------------------------------------------------------------------------
// Kernel C: causal graph. One wave per (b,i); loop j; LN+relu+dot+sigmoid.
// hj already has bg1 folded in.
// ---------------------------------------------------------------------------
__global__ __launch_bounds__(256) void graph_kernel(
    const float* __restrict__ hi, const float* __restrict__ hj,
    const float* __restrict__ gg_, const float* __restrict__ bb_,
    const float* __restrict__ Wg2, const float* __restrict__ bg2,
    float* __restrict__ out)
{
    const int wave = threadIdx.x >> 6;
    const int lane = threadIdx.x & 63;
    const int p = blockIdx.x * 4 + wave;            // p = b*V + i, p < 1536
    const int b = p / Vp;
    const int i = p - b * Vp;

    const float* hi_row = hi + (size_t)p * Hp;
    float ri[12], gg[12], bb[12], w2[12];
#pragma unroll
    for (int c = 0; c < 12; ++c) {
        int k = lane + 64 * c;
        ri[c] = hi_row[k]; gg[c] = gg_[k]; bb[c] = bb_[k]; w2[c] = Wg2[k];
    }
    const float bg2v = bg2[0];

    for (int j = 0; j < Vp; ++j) {
        const float* hj_row = hj + (size_t)(b * Vp + j) * Hp;
        float x[12];
        float s = 0.f, q = 0.f;
#pragma unroll
        for (int c = 0; c < 12; ++c) {
            x[c] = ri[c] + hj_row[lane + 64 * c];
            s += x[c]; q += x[c] * x[c];
        }
#pragma unroll
        for (int m = 1; m < 64; m <<= 1) {
            s += __shfl_xor(s, m, 64);
            q += __shfl_xor(q, m, 64);
        }
        float mu = s * (1.0f / Hp);
        float var = q * (1.0f / Hp) - mu * mu;
        float rs = rsqrtf(var + EPS);
        float pd = 0.f;
#pragma unroll
        for (int c = 0; c < 12; ++c) {
            float y = fmaxf((x[c] - mu) * rs * gg[c] + bb[c], 0.0f);
            pd = fmaf(y, w2[c], pd);
        }
        pd = wave_sum(pd);
        if (lane == 0) {
            float sc = (i == j) ? 0.0f : 1.0f / (1.0f + expf(-(pd + bg2v)));
            out[(size_t)p * Vp + j] = sc;
        }
    }
}

// ---------------------------------------------------------------------------
// Kernel D: effects. Block = one (b,i) x one 16-row j-tile.
// Phase 1: h2 tile [16][768] built in LDS (wave-parallel LN+relu).
// Phase 2: register-tiled GEMM vs Wi2, acc[16][3] per thread.
// hb already has bi1 folded in.
// ---------------------------------------------------------------------------
#define JT 16
__global__ __launch_bounds__(256) void effects_kernel(
    const float* __restrict__ ha, const float* __restrict__ hb,
    const float* __restrict__ gi_, const float* __restrict__ bi_,
    const float* __restrict__ Wi2, const float* __restrict__ bi2,
    float* __restrict__ out)
{
    __shared__ float As[JT][Hp];   // 48 KB

    const int tid = threadIdx.x;
    const int wave = tid >> 6;
    const int lane = tid & 63;
    const int bid = blockIdx.x;
    const int bi = bid / 3;        // b*I + i
    const int jt = bid - bi * 3;
    const int j0 = jt * JT;
    const int b = bi / Ip;

    // ---- Phase 1: build h2 tile in LDS ----
    const float* ha_row = ha + (size_t)bi * Hp;
    float hav[12], gv[12], bv[12];
#pragma unroll
    for (int c = 0; c < 12; ++c) {
        int k = lane + 64 * c;
        hav[c] = ha_row[k]; gv[c] = gi_[k]; bv[c] = bi_[k];
    }
    for (int jj = wave; jj < JT; jj += 4) {
        const int j = j0 + jj;
        const float* hb_row = hb + (size_t)(b * Vp + j) * Hp;
        float x[12];
        float s = 0.f, q = 0.f;
#pragma unroll
        for (int c = 0; c < 12; ++c) {
            x[c] = hav[c] + hb_row[lane + 64 * c];
            s += x[c]; q += x[c] * x[c];
        }
#pragma unroll
        for (int m = 1; m < 64; m <<= 1) {
            s += __shfl_xor(s, m, 64);
            q += __shfl_xor(q, m, 64);
        }
        float mu = s * (1.0f / Hp);
        float var = q * (1.0f / Hp) - mu * mu;
        float rs = rsqrtf(var + EPS);
#pragma unroll
        for (int c = 0; c < 12; ++c) {
            As[jj][lane + 64 * c] = fmaxf((x[c] - mu) * rs * gv[c] + bv[c], 0.0f);
        }
    }
    __syncthreads();

    // ---- Phase 2: GEMM vs Wi2 ----
    float acc[JT][3] = {};
    for (int h = 0; h < Hp; h += 2) {
        float2 a[JT];
#pragma unroll
        for (int r = 0; r < JT; ++r) a[r] = *reinterpret_cast<const float2*>(&As[r][h]);
#pragma unroll
        for (int u = 0; u < 2; ++u) {
            const float* wrow = Wi2 + (size_t)(h + u) * Hp;
            float w0 = wrow[tid], w1 = wrow[tid + 256], w2 = wrow[tid + 512];
#pragma unroll
            for (int r = 0; r < JT; ++r) {
                float av = u ? a[r].y : a[r].x;
                acc[r][0] = fmaf(av, w0, acc[r][0]);
                acc[r][1] = fmaf(av, w1, acc[r][1]);
                acc[r][2] = fmaf(av, w2, acc[r][2]);
            }
        }
    }

    const float b0 = bi2[tid], b1 = bi2[tid + 256], b2 = bi2[tid + 512];
#pragma unroll
    for (int r = 0; r < JT; ++r) {
        float* orow = out + (size_t)(bi * Vp + j0 + r) * Hp;
        orow[tid]       = acc[r][0] + b0;
        orow[tid + 256] = acc[r][1] + b1;
        orow[tid + 512] = acc[r][2] + b2;
    }
}

// ---------------------------------------------------------------------------
extern "C" void kernel_launch(void* const* d_in, const int* in_sizes, int n_in,
                              void* d_out, int out_size, void* d_ws, size_t ws_size,
                              hipStream_t stream) {
    const float* variables     = (const float*)d_in[0];
    const float* interventions = (const float*)d_in[1];
    const float* W_enc = (const float*)d_in[2];
    const float* b_enc = (const float*)d_in[3];
    const float* g_enc = (const float*)d_in[4];
    const float* be_enc = (const float*)d_in[5];
    const float* Wg1 = (const float*)d_in[6];
    const float* bg1 = (const float*)d_in[7];
    const float* g_g = (const float*)d_in[8];
    const float* b_g = (const float*)d_in[9];
    const float* Wg2 = (const float*)d_in[10];
    const float* bg2 = (const float*)d_in[11];
    const float* Wi1 = (const float*)d_in[12];
    const float* bi1 = (const float*)d_in[13];
    const float* g_i = (const float*)d_in[14];
    const float* b_i = (const float*)d_in[15];
    const float* Wi2 = (const float*)d_in[16];
    const float* bi2 = (const float*)d_in[17];

    float* out = (float*)d_out;
    float* effects = out;
    float* graph = out + EFFECTS_SIZE;
    float* enc = out + EFFECTS_SIZE + GRAPH_SIZE;

    float* ws = (float*)d_ws;
    float* hi = ws;
    float* hj = hi + ENC_SIZE;
    float* hb = hj + ENC_SIZE;
    float* ha = hb + ENC_SIZE;

    // enc = relu(LN(variables @ W_enc + b_enc))
    enc_kernel<<<(Bp*Vp)/4, 256, 0, stream>>>(variables, W_enc, b_enc, g_enc, be_enc, enc);
    // hi = enc @ Wg1[:H];  hj = enc @ Wg1[H:] + bg1
    gemm4_kernel<<<(Bp*Vp)/4, 256, 0, stream>>>(enc, Wg1, nullptr, hi);
    gemm4_kernel<<<(Bp*Vp)/4, 256, 0, stream>>>(enc, Wg1 + Hp*Hp, bg1, hj);
    // hb = enc @ Wi1[H:] + bi1;  ha = interventions @ Wi1[:H]
    gemm4_kernel<<<(Bp*Vp)/4, 256, 0, stream>>>(enc, Wi1 + Hp*Hp, bi1, hb);
    gemm4_kernel<<<(Bp*Ip)/4, 256, 0, stream>>>(interventions, Wi1, nullptr, ha);
    // causal graph
    graph_kernel<<<(Bp*Vp)/4, 256, 0, stream>>>(hi, hj, g_g, b_g, Wg2, bg2, graph);
    // effects
    effects_kernel<<<(Bp*Ip)*3, 256, 0, stream>>>(ha, hb, g_i, b_i, Wi2, bi2, effects);
}

// Round 2
// 329.716 us; speedup vs baseline: 5.1009x; 5.1009x over previous
//
#include <hip/hip_runtime.h>
#include <math.h>

#define Bp 32
#define Vp 48
#define Ip 24
#define Hp 768
#define EPS 1e-5f

#define EFFECTS_SIZE (Bp*Ip*Vp*Hp)   // 28,311,552
#define GRAPH_SIZE   (Bp*Vp*Vp)      // 73,728
#define ENC_SIZE     (Bp*Vp*Hp)      // 1,179,648
#define INT_SIZE     (Bp*Ip*Hp)      // 589,824
#define MS           (Hp*Hp)         // packed matrix size in ushorts (589,824)

typedef __attribute__((ext_vector_type(8))) short short8;
typedef __attribute__((ext_vector_type(4))) float floatx4;
typedef __attribute__((ext_vector_type(4))) unsigned int uintx4;

__device__ __forceinline__ unsigned short f2bf(float f) {
    unsigned int u = __float_as_uint(f);
    u += 0x7fffu + ((u >> 16) & 1u);
    return (unsigned short)(u >> 16);
}
__device__ __forceinline__ unsigned int f2bf2(float a, float b) {
    return (unsigned int)f2bf(a) | ((unsigned int)f2bf(b) << 16);
}

// ---------------------------------------------------------------------------
// Pack 6 H x H weight blocks into MFMA B-operand layout (bf16):
// packed[m][((T*24+kb)*64+lane)*8 + j] = W[kb*32 + (lane>>4)*8 + j][T*16 + (lane&15)]
// slots: 0=W_enc 1=Wg1a 2=Wg1b 3=Wi1b 4=Wi1a 5=Wi2  (1..3 contiguous for N=2304 GEMM)
// ---------------------------------------------------------------------------
__global__ __launch_bounds__(256) void pack_weights(
    const float* __restrict__ W_enc, const float* __restrict__ Wg1,
    const float* __restrict__ Wi1, const float* __restrict__ Wi2,
    unsigned short* __restrict__ packed)
{
    const int bid = blockIdx.x;          // 0..287
    const int m = bid / 48;
    const int T = bid - m * 48;
    const float* src;
    switch (m) {
        case 0: src = W_enc; break;
        case 1: src = Wg1; break;
        case 2: src = Wg1 + Hp * Hp; break;
        case 3: src = Wi1 + Hp * Hp; break;
        case 4: src = Wi1; break;
        default: src = Wi2; break;
    }
    unsigned short* dst = packed + (size_t)m * MS;
    const int lane = threadIdx.x & 63;
    const int kq = threadIdx.x >> 6;     // 0..3
    const int col = T * 16 + (lane & 15);
    const int krow0 = (lane >> 4) * 8;
#pragma unroll
    for (int u = 0; u < 6; ++u) {
        const int kb = kq + 4 * u;       // 0..23
        unsigned int w[4];
#pragma unroll
        for (int p2 = 0; p2 < 4; ++p2) {
            float f0 = src[(size_t)(kb * 32 + krow0 + 2 * p2)     * Hp + col];
            float f1 = src[(size_t)(kb * 32 + krow0 + 2 * p2 + 1) * Hp + col];
            w[p2] = f2bf2(f0, f1);
        }
        uintx4 v; v.x = w[0]; v.y = w[1]; v.z = w[2]; v.w = w[3];
        *(uintx4*)(dst + ((size_t)(T * 24 + kb) * 64 + lane) * 8) = v;
    }
}

// ---------------------------------------------------------------------------
// Convert variables+interventions fp32 -> bf16; block 0 also builds bias2304.
// ---------------------------------------------------------------------------
__global__ __launch_bounds__(256) void convert_inputs(
    const float* __restrict__ vars, const float* __restrict__ intv,
    const float* __restrict__ bg1, const float* __restrict__ bi1,
    unsigned short* __restrict__ varb, unsigned short* __restrict__ intvb,
    float* __restrict__ bias2304)
{
    const int p = blockIdx.x * 256 + threadIdx.x;   // pair index; grid covers exactly
    const int VPn = ENC_SIZE / 2;   // 589,824 pairs
    if (p < VPn) {
        float2 f = ((const float2*)vars)[p];
        ((unsigned int*)varb)[p] = f2bf2(f.x, f.y);
    } else {
        int q = p - VPn;
        float2 f = ((const float2*)intv)[q];
        ((unsigned int*)intvb)[q] = f2bf2(f.x, f.y);
    }
    if (blockIdx.x == 0) {
        for (int t = threadIdx.x; t < 2304; t += 256)
            bias2304[t] = (t < 768) ? 0.0f : (t < 1536 ? bg1[t - 768] : bi1[t - 1536]);
    }
}

// ---------------------------------------------------------------------------
// Generic MFMA GEMM: C[M x N] = A_bf16[M x 768] @ Bpacked (+bias), fp32 out.
// Block: 256 thr / 4 waves; tile Mt=32 (2 m-tiles), Nt=128 (wave = 32 cols).
// A staged full-K in LDS with +8 bf16 row pad (bank rotation).
// ---------------------------------------------------------------------------
__global__ __launch_bounds__(256) void gemm_mfma(
    const unsigned short* __restrict__ A, const unsigned short* __restrict__ Bpk,
    const float* __restrict__ bias, float* __restrict__ C, int ldc)
{
    __shared__ unsigned short Asl[32 * 776];
    const int tid = threadIdx.x;
    const int wave = tid >> 6, lane = tid & 63;
    const int m0 = blockIdx.x * 32;
    const int n0 = blockIdx.y * 128;

#pragma unroll
    for (int u = 0; u < 12; ++u) {
        const int chunk = tid + 256 * u;          // 3072 chunks of 8 bf16
        const int r = chunk / 96, c = chunk - r * 96;
        uintx4 v = *(const uintx4*)(A + (size_t)(m0 + r) * Hp + c * 8);
        *(uintx4*)(&Asl[r * 776 + c * 8]) = v;
    }
    __syncthreads();

    const int mrow = lane & 15, kq = lane >> 4;
    const floatx4 z = {0.f, 0.f, 0.f, 0.f};
    floatx4 acc00 = z, acc01 = z, acc10 = z, acc11 = z;
    const int Tg0 = (n0 >> 4) + wave * 2;
    const unsigned short* Bb0 = Bpk + ((size_t)(Tg0 * 24) * 64 + lane) * 8;
    const unsigned short* Bb1 = Bpk + ((size_t)((Tg0 + 1) * 24) * 64 + lane) * 8;

#pragma unroll
    for (int kb = 0; kb < 24; ++kb) {
        short8 a0 = *(const short8*)&Asl[mrow * 776 + kb * 32 + kq * 8];
        short8 a1 = *(const short8*)&Asl[(16 + mrow) * 776 + kb * 32 + kq * 8];
        short8 b0 = *(const short8*)(Bb0 + (size_t)kb * 512);
        short8 b1 = *(const short8*)(Bb1 + (size_t)kb * 512);
        acc00 = __builtin_amdgcn_mfma_f32_16x16x32_bf16(a0, b0, acc00, 0, 0, 0);
        acc01 = __builtin_amdgcn_mfma_f32_16x16x32_bf16(a0, b1, acc01, 0, 0, 0);
        acc10 = __builtin_amdgcn_mfma_f32_16x16x32_bf16(a1, b0, acc10, 0, 0, 0);
        acc11 = __builtin_amdgcn_mfma_f32_16x16x32_bf16(a1, b1, acc11, 0, 0, 0);
    }

    floatx4 acc[2][2] = {{acc00, acc01}, {acc10, acc11}};
#pragma unroll
    for (int nt = 0; nt < 2; ++nt) {
        const int colg = n0 + wave * 32 + nt * 16 + mrow;
        const float bv = bias ? bias[colg] : 0.0f;
#pragma unroll
        for (int mt = 0; mt < 2; ++mt) {
#pragma unroll
            for (int r = 0; r < 4; ++r) {
                const int row = m0 + mt * 16 + kq * 4 + r;
                C[(size_t)row * ldc + colg] = acc[mt][nt][r] + bv;
            }
        }
    }
}

// ---------------------------------------------------------------------------
// LN+ReLU over pre-activations -> enc fp32 (output) and enc bf16 (next GEMM A)
// ---------------------------------------------------------------------------
__global__ __launch_bounds__(256) void ln_relu(
    const float* __restrict__ pre, const float* __restrict__ g,
    const float* __restrict__ be, float* __restrict__ encf,
    unsigned short* __restrict__ encb)
{
    const int wave = threadIdx.x >> 6, lane = threadIdx.x & 63;
    const int row = blockIdx.x * 4 + wave;
    const float2* rp = (const float2*)(pre + (size_t)row * Hp);
    float2 x[6]; float s = 0.f, q = 0.f;
#pragma unroll
    for (int c = 0; c < 6; ++c) {
        x[c] = rp[lane + 64 * c];
        s += x[c].x + x[c].y;
        q += x[c].x * x[c].x + x[c].y * x[c].y;
    }
#pragma unroll
    for (int m = 1; m < 64; m <<= 1) { s += __shfl_xor(s, m, 64); q += __shfl_xor(q, m, 64); }
    const float mu = s * (1.0f / Hp);
    const float var = q * (1.0f / Hp) - mu * mu;
    const float rs = rsqrtf(var + EPS);
    float2* of = (float2*)(encf + (size_t)row * Hp);
    unsigned int* ob = (unsigned int*)(encb + (size_t)row * Hp);
#pragma unroll
    for (int c = 0; c < 6; ++c) {
        const float2 g2 = ((const float2*)g)[lane + 64 * c];
        const float2 b2 = ((const float2*)be)[lane + 64 * c];
        float y0 = fmaxf((x[c].x - mu) * rs * g2.x + b2.x, 0.f);
        float y1 = fmaxf((x[c].y - mu) * rs * g2.y + b2.y, 0.f);
        of[lane + 64 * c] = make_float2(y0, y1);
        ob[lane + 64 * c] = f2bf2(y0, y1);
    }
}

// ---------------------------------------------------------------------------
// Causal graph: block = (b,i); wave handles 12 j's. hi at ws2 col 0, hj at 768
// (bg1 already folded into hj via GEMM bias).
// ---------------------------------------------------------------------------
__global__ __launch_bounds__(256) void graph_kernel(
    const float* __restrict__ ws2, const float* __restrict__ gg_,
    const float* __restrict__ bb_, const float* __restrict__ Wg2,
    const float* __restrict__ bg2, float* __restrict__ out)
{
    const int wave = threadIdx.x >> 6, lane = threadIdx.x & 63;
    const int p = blockIdx.x;                 // b*V + i
    const int b = p / Vp, i = p - b * Vp;
    const float* hi_row = ws2 + (size_t)p * 2304;
    float ri[12], gg[12], bb[12], w2[12];
#pragma unroll
    for (int c = 0; c < 12; ++c) {
        const int k = lane + 64 * c;
        ri[c] = hi_row[k]; gg[c] = gg_[k]; bb[c] = bb_[k]; w2[c] = Wg2[k];
    }
    const float bg2v = bg2[0];
    const int j0 = wave * 12;
    for (int jj = 0; jj < 12; ++jj) {
        const int j = j0 + jj;
        const float* hj_row = ws2 + (size_t)(b * Vp + j) * 2304 + 768;
        float x[12], s = 0.f, q = 0.f;
#pragma unroll
        for (int c = 0; c < 12; ++c) {
            x[c] = ri[c] + hj_row[lane + 64 * c];
            s += x[c]; q += x[c] * x[c];
        }
#pragma unroll
        for (int m = 1; m < 64; m <<= 1) { s += __shfl_xor(s, m, 64); q += __shfl_xor(q, m, 64); }
        const float mu = s * (1.0f / Hp);
        const float var = q * (1.0f / Hp) - mu * mu;
        const float rs = rsqrtf(var + EPS);
        float pd = 0.f;
#pragma unroll
        for (int c = 0; c < 12; ++c) {
            float y = fmaxf((x[c] - mu) * rs * gg[c] + bb[c], 0.f);
            pd = fmaf(y, w2[c], pd);
        }
#pragma unroll
        for (int m = 1; m < 64; m <<= 1) pd += __shfl_xor(pd, m, 64);
        if (lane == 0) {
            float sc = (i == j) ? 0.0f : 1.0f / (1.0f + expf(-(pd + bg2v)));
            out[(size_t)p * Vp + j] = sc;
        }
    }
}

// ---------------------------------------------------------------------------
// Effects: block = 32 rows of the virtual [36864 x 768] h2 matrix.
// Phase 1: LN+ReLU -> bf16 LDS tile (row pad 776). Phase 2: MFMA vs packed Wi2.
// (bi1 folded into hb via GEMM bias.)
// ---------------------------------------------------------------------------
__global__ __launch_bounds__(256) void effects_mfma(
    const float* __restrict__ ha, const float* __restrict__ ws2,
    const float* __restrict__ g_i, const float* __restrict__ b_i,
    const unsigned short* __restrict__ Bpk, const float* __restrict__ bi2,
    float* __restrict__ out)
{
    __shared__ unsigned short Asl[32 * 776];
    const int tid = threadIdx.x, wave = tid >> 6, lane = tid & 63;
    const int m0 = blockIdx.x * 32;

    float2 gv[6], bv[6];
#pragma unroll
    for (int c = 0; c < 6; ++c) {
        gv[c] = ((const float2*)g_i)[lane + 64 * c];
        bv[c] = ((const float2*)b_i)[lane + 64 * c];
    }

#pragma unroll
    for (int u = 0; u < 8; ++u) {
        const int lr = wave * 8 + u;
        const int r = m0 + lr;
        const int bi = r / 48, j = r - bi * 48;
        const int b = bi / Ip;
        const float2* hap = (const float2*)(ha + (size_t)bi * Hp);
        const float2* hbp = (const float2*)(ws2 + (size_t)(b * Vp + j) * 2304 + 1536);
        float2 x[6]; float s = 0.f, q = 0.f;
#pragma unroll
        for (int c = 0; c < 6; ++c) {
            float2 a2 = hap[lane + 64 * c];
            float2 h2 = hbp[lane + 64 * c];
            x[c].x = a2.x + h2.x; x[c].y = a2.y + h2.y;
            s += x[c].x + x[c].y;
            q += x[c].x * x[c].x + x[c].y * x[c].y;
        }
#pragma unroll
        for (int m = 1; m < 64; m <<= 1) { s += __shfl_xor(s, m, 64); q += __shfl_xor(q, m, 64); }
        const float mu = s * (1.0f / Hp);
        const float var = q * (1.0f / Hp) - mu * mu;
        const float rs = rsqrtf(var + EPS);
#pragma unroll
        for (int c = 0; c < 6; ++c) {
            float y0 = fmaxf((x[c].x - mu) * rs * gv[c].x + bv[c].x, 0.f);
            float y1 = fmaxf((x[c].y - mu) * rs * gv[c].y + bv[c].y, 0.f);
            *(unsigned int*)(&Asl[lr * 776 + (lane + 64 * c) * 2]) = f2bf2(y0, y1);
        }
    }
    __syncthreads();

    const int mrow = lane & 15, kq = lane >> 4;
    const floatx4 z = {0.f, 0.f, 0.f, 0.f};
#pragma unroll
    for (int G = 0; G < 4; ++G) {
        const int Tg = wave * 12 + G * 3;
        floatx4 acc[2][3];
#pragma unroll
        for (int mt = 0; mt < 2; ++mt)
#pragma unroll
            for (int nt = 0; nt < 3; ++nt) acc[mt][nt] = z;
        const unsigned short* Bb0 = Bpk + ((size_t)((Tg + 0) * 24) * 64 + lane) * 8;
        const unsigned short* Bb1 = Bpk + ((size_t)((Tg + 1) * 24) * 64 + lane) * 8;
        const unsigned short* Bb2 = Bpk + ((size_t)((Tg + 2) * 24) * 64 + lane) * 8;
#pragma unroll
        for (int kb = 0; kb < 24; ++kb) {
            short8 a0 = *(const short8*)&Asl[mrow * 776 + kb * 32 + kq * 8];
            short8 a1 = *(const short8*)&Asl[(16 + mrow) * 776 + kb * 32 + kq * 8];
            short8 b0 = *(const short8*)(Bb0 + (size_t)kb * 512);
            short8 b1 = *(const short8*)(Bb1 + (size_t)kb * 512);
            short8 b2 = *(const short8*)(Bb2 + (size_t)kb * 512);
            acc[0][0] = __builtin_amdgcn_mfma_f32_16x16x32_bf16(a0, b0, acc[0][0], 0, 0, 0);
            acc[1][0] = __builtin_amdgcn_mfma_f32_16x16x32_bf16(a1, b0, acc[1][0], 0, 0, 0);
            acc[0][1] = __builtin_amdgcn_mfma_f32_16x16x32_bf16(a0, b1, acc[0][1], 0, 0, 0);
            acc[1][1] = __builtin_amdgcn_mfma_f32_16x16x32_bf16(a1, b1, acc[1][1], 0, 0, 0);
            acc[0][2] = __builtin_amdgcn_mfma_f32_16x16x32_bf16(a0, b2, acc[0][2], 0, 0, 0);
            acc[1][2] = __builtin_amdgcn_mfma_f32_16x16x32_bf16(a1, b2, acc[1][2], 0, 0, 0);
        }
#pragma unroll
        for (int nt = 0; nt < 3; ++nt) {
            const int colg = (Tg + nt) * 16 + mrow;
            const float biasv = bi2[colg];
#pragma unroll
            for (int mt = 0; mt < 2; ++mt) {
#pragma unroll
                for (int r = 0; r < 4; ++r) {
                    const int row = m0 + mt * 16 + kq * 4 + r;
                    out[(size_t)row * Hp + colg] = acc[mt][nt][r] + biasv;
                }
            }
        }
    }
}

// ---------------------------------------------------------------------------
extern "C" void kernel_launch(void* const* d_in, const int* in_sizes, int n_in,
                              void* d_out, int out_size, void* d_ws, size_t ws_size,
                              hipStream_t stream) {
    const float* variables     = (const float*)d_in[0];
    const float* interventions = (const float*)d_in[1];
    const float* W_enc  = (const float*)d_in[2];
    const float* b_enc  = (const float*)d_in[3];
    const float* g_enc  = (const float*)d_in[4];
    const float* be_enc = (const float*)d_in[5];
    const float* Wg1 = (const float*)d_in[6];
    const float* bg1 = (const float*)d_in[7];
    const float* g_g = (const float*)d_in[8];
    const float* b_g = (const float*)d_in[9];
    const float* Wg2 = (const float*)d_in[10];
    const float* bg2 = (const float*)d_in[11];
    const float* Wi1 = (const float*)d_in[12];
    const float* bi1 = (const float*)d_in[13];
    const float* g_i = (const float*)d_in[14];
    const float* b_i = (const float*)d_in[15];
    const float* Wi2 = (const float*)d_in[16];
    const float* bi2 = (const float*)d_in[17];

    float* out = (float*)d_out;
    float* effects = out;
    float* graph = out + EFFECTS_SIZE;
    float* enc_f = out + EFFECTS_SIZE + GRAPH_SIZE;

    // ws layout (bytes):
    char* wsb = (char*)d_ws;
    unsigned short* packedW = (unsigned short*)wsb;                   // 7,077,888 B
    float* ws2  = (float*)(wsb + 7077888);                            // [1536][2304] fp32 = 14,155,776 B
    float* pre1 = ws2;                                                // aliases ws2 start (consumed before ws2 written)
    float* ha   = (float*)(wsb + 7077888 + 14155776);                 // [768][768] fp32 = 2,359,296 B
    unsigned short* varb  = (unsigned short*)(wsb + 23592960);        // 2,359,296 B
    unsigned short* intvb = (unsigned short*)(wsb + 25952256);        // 1,179,648 B
    unsigned short* encb  = (unsigned short*)(wsb + 27131904);        // 2,359,296 B
    float* bias2304 = (float*)(wsb + 29491200);                       // 9,216 B

    pack_weights<<<288, 256, 0, stream>>>(W_enc, Wg1, Wi1, Wi2, packedW);
    convert_inputs<<<3456, 256, 0, stream>>>(variables, interventions, bg1, bi1,
                                             varb, intvb, bias2304);
    // pre1 = var @ W_enc + b_enc
    gemm_mfma<<<dim3(48, 6), 256, 0, stream>>>(varb, packedW, b_enc, pre1, Hp);
    // enc (fp32 to d_out, bf16 to ws)
    ln_relu<<<384, 256, 0, stream>>>(pre1, g_enc, be_enc, enc_f, encb);
    // ws2 = enc @ [Wg1a | Wg1b | Wi1b] + [0 | bg1 | bi1]   (N=2304)
    gemm_mfma<<<dim3(48, 18), 256, 0, stream>>>(encb, packedW + (size_t)1 * MS,
                                                bias2304, ws2, 2304);
    // ha = intv @ Wi1a
    gemm_mfma<<<dim3(24, 6), 256, 0, stream>>>(intvb, packedW + (size_t)4 * MS,
                                               nullptr, ha, Hp);
    graph_kernel<<<Bp * Vp, 256, 0, stream>>>(ws2, g_g, b_g, Wg2, bg2, graph);
    effects_mfma<<<(Bp * Ip * Vp) / 32, 256, 0, stream>>>(ha, ws2, g_i, b_i,
                                                          packedW + (size_t)5 * MS,
                                                          bi2, effects);
}